// Round 1
// baseline (3824.776 us; speedup 1.0000x reference)
//
#include <hip/hip_runtime.h>
#include <cmath>

#define BB 16
#define CC 128
#define HH 128
#define WW 128
#define NN 1024
#define SS 256
#define FIN 130
#define NMID 6
#define BN (BB*NN)

// ---------------------------------------------------------------------------
// Bilinear interpolation + concat(base_point) -> X (BN x 130)
// ---------------------------------------------------------------------------
__global__ void k_interp(const float* __restrict__ features,
                         const float* __restrict__ base_point,
                         float* __restrict__ X) {
    int bn = blockIdx.x;           // 0..BN-1
    int c  = threadIdx.x;          // 0..127
    int b  = bn >> 10;
    float px = base_point[bn * 2 + 0];
    float py = base_point[bn * 2 + 1];
    float Xs = px * WW, Ys = py * HH;
    float X0f = floorf(Xs), Y0f = floorf(Ys);
    float X1f = X0f + 1.f, Y1f = Y0f + 1.f;
    float w00 = (X1f - Xs) * (Y1f - Ys);
    float w01 = (X1f - Xs) * (Ys - Y0f);
    float w10 = (Xs - X0f) * (Y1f - Ys);
    float w11 = (Xs - X0f) * (Ys - Y0f);
    int x0 = min(max((int)X0f, 0), WW - 1);
    int x1 = min(max((int)X1f, 0), WW - 1);
    int y0 = min(max((int)Y0f, 0), HH - 1);
    int y1 = min(max((int)Y1f, 0), HH - 1);
    const float* fb = features + ((size_t)(b * CC + c)) * (HH * WW);
    float v = w00 * fb[y0 * WW + x0] + w01 * fb[y1 * WW + x0] +
              w10 * fb[y0 * WW + x1] + w11 * fb[y1 * WW + x1];
    X[(size_t)bn * FIN + c] = v;
    if (c < 2) X[(size_t)bn * FIN + CC + c] = base_point[bn * 2 + c];
}

// ---------------------------------------------------------------------------
// Batched agg = adj @ src : per batch (1024x1024)*(1024xD), D<=256
// grid: (ceil(D/64), NN/64, BB), block 256
// ---------------------------------------------------------------------------
__global__ __launch_bounds__(256) void k_agg(const float* __restrict__ adj,
                                             const float* __restrict__ src, int lds,
                                             float* __restrict__ dst, int ldd, int D) {
    __shared__ float As[16][68];
    __shared__ float Bs[16][68];
    int b  = blockIdx.z;
    int r0 = blockIdx.y * 64;
    int c0 = blockIdx.x * 64;
    int t  = threadIdx.x;
    int tx = t & 15, ty = t >> 4;
    const float* A = adj + (size_t)b * NN * NN;
    const float* S = src + (size_t)b * NN * lds;
    float acc[4][4] = {};
    for (int kt = 0; kt < NN; kt += 16) {
        {   // A tile 64 rows x 16 k, float4 loads
            int i = t >> 2, kq = (t & 3) * 4;
            const float4 av = *(const float4*)(A + (size_t)(r0 + i) * NN + kt + kq);
            As[kq + 0][i] = av.x; As[kq + 1][i] = av.y;
            As[kq + 2][i] = av.z; As[kq + 3][i] = av.w;
        }
        {   // B tile 16 k x 64 cols (scalar, bounds on D)
            int k = t >> 4, j = (t & 15) * 4;
            const float* Srow = S + (size_t)(kt + k) * lds;
            #pragma unroll
            for (int q = 0; q < 4; ++q) {
                int c = c0 + j + q;
                Bs[k][j + q] = (c < D) ? Srow[c] : 0.f;
            }
        }
        __syncthreads();
        #pragma unroll
        for (int kk = 0; kk < 16; ++kk) {
            float4 a  = *(const float4*)&As[kk][ty * 4];
            float4 bv = *(const float4*)&Bs[kk][tx * 4];
            float av[4] = {a.x, a.y, a.z, a.w};
            float bb[4] = {bv.x, bv.y, bv.z, bv.w};
            #pragma unroll
            for (int mi = 0; mi < 4; ++mi)
                #pragma unroll
                for (int ni = 0; ni < 4; ++ni)
                    acc[mi][ni] += av[mi] * bb[ni];
        }
        __syncthreads();
    }
    float* Dp = dst + (size_t)b * NN * ldd;
    #pragma unroll
    for (int mi = 0; mi < 4; ++mi) {
        int r = r0 + ty * 4 + mi;
        #pragma unroll
        for (int ni = 0; ni < 4; ++ni) {
            int c = c0 + tx * 4 + ni;
            if (c < D) Dp[(size_t)r * ldd + c] = acc[mi][ni];
        }
    }
}

// ---------------------------------------------------------------------------
// Fused gconv: out = act( X@W0^T + AGG@W1^T + b0 + b1 [+res] )
// rows = BN (batch-flattened), cols = 256, K = 130 or 256
// grid: (SS/64, BN/64), block 256
// ---------------------------------------------------------------------------
__global__ __launch_bounds__(256) void k_gconv(
        const float* __restrict__ Xp, int ldx,
        const float* __restrict__ Ag,
        const float* __restrict__ W0, const float* __restrict__ W1, int K,
        const float* __restrict__ b0, const float* __restrict__ b1,
        const float* __restrict__ res, int relu,
        float* __restrict__ out) {
    __shared__ float A0[16][68], A1[16][68], B0[16][68], B1[16][68];
    int r0 = blockIdx.y * 64;
    int c0 = blockIdx.x * 64;
    int t  = threadIdx.x;
    int tx = t & 15, ty = t >> 4;
    float acc[4][4] = {};
    int KT = (K + 15) / 16;
    for (int kti = 0; kti < KT; ++kti) {
        int kt = kti * 16;
        {   // A tiles (X and AGG): 64 rows x 16 k, scalar bounds on K
            int i = t >> 2, kq = (t & 3) * 4;
            const float* xr = Xp + (size_t)(r0 + i) * ldx;
            const float* ar = Ag + (size_t)(r0 + i) * SS;
            #pragma unroll
            for (int q = 0; q < 4; ++q) {
                int k = kt + kq + q;
                A0[kq + q][i] = (k < K) ? xr[k] : 0.f;
                A1[kq + q][i] = (k < K) ? ar[k] : 0.f;
            }
        }
        {   // W tiles (transposed stage): 16 k x 64 s
            int k = t & 15, s4 = (t >> 4) * 4;
            #pragma unroll
            for (int q = 0; q < 4; ++q) {
                int s  = c0 + s4 + q;
                int kk = kt + k;
                B0[k][s4 + q] = (kk < K) ? W0[(size_t)s * K + kk] : 0.f;
                B1[k][s4 + q] = (kk < K) ? W1[(size_t)s * K + kk] : 0.f;
            }
        }
        __syncthreads();
        #pragma unroll
        for (int kk = 0; kk < 16; ++kk) {
            float4 a0 = *(const float4*)&A0[kk][ty * 4];
            float4 a1 = *(const float4*)&A1[kk][ty * 4];
            float4 w0 = *(const float4*)&B0[kk][tx * 4];
            float4 w1 = *(const float4*)&B1[kk][tx * 4];
            float aa0[4] = {a0.x, a0.y, a0.z, a0.w};
            float aa1[4] = {a1.x, a1.y, a1.z, a1.w};
            float ww0[4] = {w0.x, w0.y, w0.z, w0.w};
            float ww1[4] = {w1.x, w1.y, w1.z, w1.w};
            #pragma unroll
            for (int mi = 0; mi < 4; ++mi)
                #pragma unroll
                for (int ni = 0; ni < 4; ++ni)
                    acc[mi][ni] += aa0[mi] * ww0[ni] + aa1[mi] * ww1[ni];
        }
        __syncthreads();
    }
    #pragma unroll
    for (int mi = 0; mi < 4; ++mi) {
        int r = r0 + ty * 4 + mi;
        #pragma unroll
        for (int ni = 0; ni < 4; ++ni) {
            int c = c0 + tx * 4 + ni;
            float v = acc[mi][ni] + b0[c] + b1[c];
            if (res) v += res[(size_t)r * SS + c];
            if (relu) v = fmaxf(v, 0.f);
            out[(size_t)r * SS + c] = v;
        }
    }
}

// ---------------------------------------------------------------------------
// FC head: pred = H@fcW^T + fcb ; writes poly & pred outputs, G = pred*mask
// ---------------------------------------------------------------------------
__global__ void k_fc(const float* __restrict__ Hf,
                     const float* __restrict__ fcW, const float* __restrict__ fcb,
                     const float* __restrict__ base_point,
                     const float* __restrict__ mask,
                     float* __restrict__ out, float* __restrict__ G) {
    int bn = blockIdx.x * blockDim.x + threadIdx.x;
    if (bn >= BN) return;
    const float* hr = Hf + (size_t)bn * SS;
    float a0 = fcb[0], a1 = fcb[1];
    for (int k = 0; k < SS; ++k) {
        float v = hr[k];
        a0 += v * fcW[k];
        a1 += v * fcW[SS + k];
    }
    float m  = mask[bn];
    float p0 = base_point[bn * 2 + 0], p1 = base_point[bn * 2 + 1];
    float g0 = a0 * m, g1 = a1 * m;
    out[16 + bn * 2 + 0] = p0 + g0;            // gcn_pred_poly
    out[16 + bn * 2 + 1] = p1 + g1;
    out[16 + BN * 2 + bn * 2 + 0] = a0;        // gcn_pred
    out[16 + BN * 2 + bn * 2 + 1] = a1;
    G[bn * 2 + 0] = g0;
    G[bn * 2 + 1] = g1;
}

// ---------------------------------------------------------------------------
// Laplacian energy: lap2-lap1 == g - adj@g  (stable form). AG = adj@G given.
// ---------------------------------------------------------------------------
__global__ __launch_bounds__(256) void k_energy(const float* __restrict__ G,
                                                const float* __restrict__ AG,
                                                float* __restrict__ out) {
    __shared__ float red[256];
    int b = blockIdx.x;
    int t = threadIdx.x;
    float s = 0.f;
    for (int n = t; n < NN; n += 256) {
        int bn = b * NN + n;
        float dx = G[bn * 2 + 0] - AG[bn * 2 + 0];
        float dy = G[bn * 2 + 1] - AG[bn * 2 + 1];
        s += sqrtf(dx * dx + dy * dy + 1e-10f);
    }
    red[t] = s;
    __syncthreads();
    for (int off = 128; off > 0; off >>= 1) {
        if (t < off) red[t] += red[t + off];
        __syncthreads();
    }
    if (t == 0) out[b] = red[0] / (float)NN;
}

// ---------------------------------------------------------------------------
extern "C" void kernel_launch(void* const* d_in, const int* in_sizes, int n_in,
                              void* d_out, int out_size, void* d_ws, size_t ws_size,
                              hipStream_t stream) {
    const float* features   = (const float*)d_in[0];
    const float* base_point = (const float*)d_in[1];
    const float* adj        = (const float*)d_in[2];
    const float* mask       = (const float*)d_in[3];
    const float* first_W    = (const float*)d_in[4];
    const float* first_b    = (const float*)d_in[5];
    const float* mid_W      = (const float*)d_in[6];
    const float* mid_b      = (const float*)d_in[7];
    const float* last_W     = (const float*)d_in[8];
    const float* last_b     = (const float*)d_in[9];
    const float* fc_W       = (const float*)d_in[10];
    const float* fc_b       = (const float*)d_in[11];
    float* out = (float*)d_out;
    float* ws  = (float*)d_ws;

    float* X   = ws;                          // BN*130
    float* AGG = X   + (size_t)BN * FIN;      // BN*256
    float* Hb  = AGG + (size_t)BN * SS;       // BN*256
    float* O1  = Hb  + (size_t)BN * SS;       // BN*256
    float* G   = O1  + (size_t)BN * SS;       // BN*2
    float* AG  = G   + (size_t)BN * 2;        // BN*2

    dim3 blk(256);

    k_interp<<<BN, 128, 0, stream>>>(features, base_point, X);

    // first gconv (K=130)
    k_agg<<<dim3(3, NN / 64, BB), blk, 0, stream>>>(adj, X, FIN, AGG, SS, FIN);
    k_gconv<<<dim3(4, BN / 64), blk, 0, stream>>>(
        X, FIN, AGG, first_W, first_W + (size_t)SS * FIN, FIN,
        first_b, first_b + SS, nullptr, 1, Hb);

    for (int i = 0; i < NMID; ++i) {
        const float* W  = mid_W + (size_t)i * 4 * SS * SS;
        const float* bb = mid_b + (size_t)i * 4 * SS;
        k_agg<<<dim3(4, NN / 64, BB), blk, 0, stream>>>(adj, Hb, SS, AGG, SS, SS);
        k_gconv<<<dim3(4, BN / 64), blk, 0, stream>>>(
            Hb, SS, AGG, W, W + (size_t)SS * SS, SS,
            bb, bb + SS, nullptr, 1, O1);
        k_agg<<<dim3(4, NN / 64, BB), blk, 0, stream>>>(adj, O1, SS, AGG, SS, SS);
        k_gconv<<<dim3(4, BN / 64), blk, 0, stream>>>(
            O1, SS, AGG, W + (size_t)2 * SS * SS, W + (size_t)3 * SS * SS, SS,
            bb + 2 * SS, bb + 3 * SS, Hb, 1, Hb);
    }

    // last gconv
    k_agg<<<dim3(4, NN / 64, BB), blk, 0, stream>>>(adj, Hb, SS, AGG, SS, SS);
    k_gconv<<<dim3(4, BN / 64), blk, 0, stream>>>(
        Hb, SS, AGG, last_W, last_W + (size_t)SS * SS, SS,
        last_b, last_b + SS, nullptr, 1, O1);

    // head + energy
    k_fc<<<BN / 256, 256, 0, stream>>>(O1, fc_W, fc_b, base_point, mask, out, G);
    k_agg<<<dim3(1, NN / 64, BB), blk, 0, stream>>>(adj, G, 2, AG, 2, 2);
    k_energy<<<BB, 256, 0, stream>>>(G, AG, out);
}

// Round 2
// 889.084 us; speedup vs baseline: 4.3019x; 4.3019x over previous
//
#include <hip/hip_runtime.h>
#include <cmath>

#define BB 16
#define CC 128
#define HH 128
#define WW 128
#define NN 1024
#define SS 256
#define BN (BB*NN)
#define K1 192            // first-layer K padded: 130 -> 192 (3 x 64)

typedef short short8v __attribute__((ext_vector_type(8)));
typedef float f32x4 __attribute__((ext_vector_type(4)));
typedef unsigned short u16;

__device__ __forceinline__ u16 f2bf(float f) {
    unsigned u = __builtin_bit_cast(unsigned, f);
    unsigned r = (u + 0x7FFFu + ((u >> 16) & 1u)) >> 16;
    return (u16)r;
}
__device__ __forceinline__ float bf2f(u16 h) {
    unsigned u = ((unsigned)h) << 16;
    return __builtin_bit_cast(float, u);
}

// ---------------------------------------------------------------------------
// casts
// ---------------------------------------------------------------------------
__global__ void k_cast4(const float* __restrict__ s, u16* __restrict__ d, long n4) {
    long i = (long)blockIdx.x * blockDim.x + threadIdx.x;
    long st = (long)gridDim.x * blockDim.x;
    for (; i < n4; i += st) {
        float4 v = ((const float4*)s)[i];
        ushort4 o;
        o.x = f2bf(v.x); o.y = f2bf(v.y); o.z = f2bf(v.z); o.w = f2bf(v.w);
        ((ushort4*)d)[i] = o;
    }
}

// first_W [2][256][130] -> bf16 [2][256][192] zero-padded
__global__ void k_castW1(const float* __restrict__ s, u16* __restrict__ d) {
    int idx = blockIdx.x * blockDim.x + threadIdx.x;
    if (idx >= 2 * 256 * K1) return;
    int k = idx % K1, r = idx / K1;
    d[idx] = (k < 130) ? f2bf(s[r * 130 + k]) : (u16)0;
}

// ---------------------------------------------------------------------------
// interp: bilinear gather -> Xh [BN][192] bf16 (pad 130..191 = 0)
//                        and XhT [16][256][1024] bf16 (rows 130..255 = 0)
// ---------------------------------------------------------------------------
__global__ void k_interp(const float* __restrict__ features,
                         const float* __restrict__ base_point,
                         u16* __restrict__ Xh, u16* __restrict__ XhT) {
    int bn = blockIdx.x;
    int c  = threadIdx.x;          // 0..127
    int b  = bn >> 10, n = bn & 1023;
    float px = base_point[bn * 2 + 0];
    float py = base_point[bn * 2 + 1];
    float Xs = px * WW, Ys = py * HH;
    float X0f = floorf(Xs), Y0f = floorf(Ys);
    float X1f = X0f + 1.f, Y1f = Y0f + 1.f;
    float w00 = (X1f - Xs) * (Y1f - Ys);
    float w01 = (X1f - Xs) * (Ys - Y0f);
    float w10 = (Xs - X0f) * (Y1f - Ys);
    float w11 = (Xs - X0f) * (Ys - Y0f);
    int x0 = min(max((int)X0f, 0), WW - 1);
    int x1 = min(max((int)X1f, 0), WW - 1);
    int y0 = min(max((int)Y0f, 0), HH - 1);
    int y1 = min(max((int)Y1f, 0), HH - 1);
    const float* fb = features + ((size_t)(b * CC + c)) * (HH * WW);
    float v = w00 * fb[y0 * WW + x0] + w01 * fb[y1 * WW + x0] +
              w10 * fb[y0 * WW + x1] + w11 * fb[y1 * WW + x1];
    u16 hv = f2bf(v);
    Xh[(long)bn * K1 + c] = hv;
    XhT[((long)b * 256 + c) * 1024 + n] = hv;
    float pv = (c < 2) ? base_point[bn * 2 + c] : 0.f;
    u16 ph = (c < 2) ? f2bf(pv) : (u16)0;
    if (c < 64) Xh[(long)bn * K1 + 128 + c] = ph;           // cols 128..191
    XhT[((long)b * 256 + 128 + c) * 1024 + n] = ph;          // rows 128..255
}

// ---------------------------------------------------------------------------
// MFMA GEMM: C = [A0|A1] @ [B0|B1]^T  (+bias +res, relu), bf16 in, f32 acc
// A: row-major [M][K] k-contig. B given as B^T: [n][K] k-contig.
// Tiles 128x128, BK=64, 4 waves of 64x64. global_load_lds w/ pre-swizzled src.
// outN: bf16 [m][ldoN]. outT (opt): bf16 [b][256][1024] transposed.
// batched: A0/B0/outN stride by blockIdx.z.
// ---------------------------------------------------------------------------
__global__ __launch_bounds__(256) void k_mm(
    const u16* __restrict__ A0, int lda0,
    const u16* __restrict__ A1, int lda1,
    const u16* __restrict__ B0, const u16* __restrict__ B1, int ldb,
    int nK,
    const float* __restrict__ bias0, const float* __restrict__ bias1,
    const u16* __restrict__ res, int do_relu,
    u16* __restrict__ outN, int ldoN,
    u16* __restrict__ outT,
    int batched, long sA, long sB, long sC) {

    __shared__ u16 lds[17408];                 // 34816 B (staging 32KB / T 34KB)
    u16* As = lds;
    u16* Bs = lds + 8192;

    int t = threadIdx.x;
    int lane = t & 63, w = t >> 6;
    int wr = w >> 1, wc = w & 1;
    int c0 = blockIdx.x * 128;
    long row0 = (long)blockIdx.y * 128;
    const u16* Ab0 = A0;
    const u16* Bb0 = B0;
    u16* oN = outN;
    if (batched) {
        int b = blockIdx.z;
        Ab0 += (long)b * sA;
        Bb0 += (long)b * sB;
        oN  += (long)b * sC;
    }

    f32x4 acc[4][4] = {};

    int totSteps = A1 ? 2 * nK : nK;
    for (int s = 0; s < totSteps; ++s) {
        const u16* Ap; int lda; const u16* Bp; int kt;
        if (s < nK) { Ap = Ab0; lda = lda0; Bp = Bb0; kt = s * 64; }
        else        { Ap = A1;  lda = lda1; Bp = B1;  kt = (s - nK) * 64; }
        #pragma unroll
        for (int q = 0; q < 4; ++q) {
            int rb = (w * 4 + q) * 8;
            int row = rb + (lane >> 3);
            int slot = lane & 7;
            int koff = kt + ((slot ^ (row & 7)) << 3);
            const u16* srcA = Ap + (row0 + row) * lda + koff;
            __builtin_amdgcn_global_load_lds(
                (const __attribute__((address_space(1))) void*)srcA,
                (__attribute__((address_space(3))) void*)(As + rb * 64), 16, 0, 0);
            const u16* srcB = Bp + (long)(c0 + row) * ldb + koff;
            __builtin_amdgcn_global_load_lds(
                (const __attribute__((address_space(1))) void*)srcB,
                (__attribute__((address_space(3))) void*)(Bs + rb * 64), 16, 0, 0);
        }
        __syncthreads();
        #pragma unroll
        for (int kk = 0; kk < 2; ++kk) {
            short8v a[4], bf[4];
            #pragma unroll
            for (int m = 0; m < 4; ++m) {
                int row = wr * 64 + m * 16 + (lane & 15);
                int sl = (kk * 4 + (lane >> 4)) ^ (row & 7);
                a[m] = *(const short8v*)(As + row * 64 + sl * 8);
            }
            #pragma unroll
            for (int n = 0; n < 4; ++n) {
                int row = wc * 64 + n * 16 + (lane & 15);
                int sl = (kk * 4 + (lane >> 4)) ^ (row & 7);
                bf[n] = *(const short8v*)(Bs + row * 64 + sl * 8);
            }
            #pragma unroll
            for (int m = 0; m < 4; ++m)
                #pragma unroll
                for (int n = 0; n < 4; ++n)
                    acc[m][n] = __builtin_amdgcn_mfma_f32_16x16x32_bf16(
                        a[m], bf[n], acc[m][n], 0, 0, 0);
        }
        __syncthreads();
    }

    // ---- epilogue ----
    int mbase = wr * 64, nbase = wc * 64;
    u16 vals[4][4][4];
    #pragma unroll
    for (int m = 0; m < 4; ++m)
        #pragma unroll
        for (int n = 0; n < 4; ++n)
            #pragma unroll
            for (int r = 0; r < 4; ++r) {
                int rr = mbase + m * 16 + (lane >> 4) * 4 + r;
                int cc = nbase + n * 16 + (lane & 15);
                long grow = row0 + rr;
                int gcol = c0 + cc;
                float v = acc[m][n][r];
                if (bias0) v += bias0[gcol] + bias1[gcol];
                if (res)   v += bf2f(res[grow * ldoN + gcol]);
                if (do_relu) v = fmaxf(v, 0.f);
                u16 hv = f2bf(v);
                oN[grow * ldoN + gcol] = hv;
                vals[m][n][r] = hv;
            }

    if (outT) {
        u16 (*T)[136] = (u16(*)[136])lds;      // 128 x 136 bf16 = 34816 B
        __syncthreads();
        #pragma unroll
        for (int m = 0; m < 4; ++m)
            #pragma unroll
            for (int n = 0; n < 4; ++n)
                #pragma unroll
                for (int r = 0; r < 4; ++r) {
                    int rr = mbase + m * 16 + (lane >> 4) * 4 + r;
                    int cc = nbase + n * 16 + (lane & 15);
                    T[cc][rr] = vals[m][n][r];
                }
        __syncthreads();
        int bb2 = (int)(row0 >> 10);
        long nodeBase = row0 & 1023;
        #pragma unroll
        for (int q2 = 0; q2 < 8; ++q2) {
            int c = (t >> 4) + q2 * 16;
            int moff = (t & 15) * 8;
            short8v vv = *(const short8v*)(&T[c][moff]);
            *(short8v*)(outT + ((long)bb2 * 256 + c0 + c) * 1024 + nodeBase + moff) = vv;
        }
    }
}

// ---------------------------------------------------------------------------
// FC head
// ---------------------------------------------------------------------------
__global__ void k_fc(const u16* __restrict__ Hf,
                     const float* __restrict__ fcW, const float* __restrict__ fcb,
                     const float* __restrict__ base_point,
                     const float* __restrict__ mask,
                     float* __restrict__ out, float* __restrict__ G) {
    int bn = blockIdx.x * blockDim.x + threadIdx.x;
    if (bn >= BN) return;
    const u16* hr = Hf + (long)bn * SS;
    float a0 = fcb[0], a1 = fcb[1];
    for (int k = 0; k < SS; k += 8) {
        short8v v = *(const short8v*)(hr + k);
        #pragma unroll
        for (int j = 0; j < 8; ++j) {
            float f = bf2f((u16)v[j]);
            a0 += f * fcW[k + j];
            a1 += f * fcW[SS + k + j];
        }
    }
    float m  = mask[bn];
    float p0 = base_point[bn * 2 + 0], p1 = base_point[bn * 2 + 1];
    float g0 = a0 * m, g1 = a1 * m;
    out[16 + bn * 2 + 0] = p0 + g0;
    out[16 + bn * 2 + 1] = p1 + g1;
    out[16 + BN * 2 + bn * 2 + 0] = a0;
    out[16 + BN * 2 + bn * 2 + 1] = a1;
    G[bn * 2 + 0] = g0;
    G[bn * 2 + 1] = g1;
}

// ---------------------------------------------------------------------------
// AG = adj @ G (fp32 G, bf16 adj); one wave per output row
// ---------------------------------------------------------------------------
__global__ __launch_bounds__(256) void k_adjg(const u16* __restrict__ adjh,
                                              const float* __restrict__ G,
                                              float* __restrict__ AG) {
    int w = threadIdx.x >> 6, lane = threadIdx.x & 63;
    long row = (long)blockIdx.x * 4 + w;
    int b = (int)(row >> 10);
    const u16* ar = adjh + ((long)b * NN + (row & 1023)) * NN;
    const float* Gb = G + (long)b * NN * 2;
    float s0 = 0.f, s1 = 0.f;
    int k0 = lane * 16;
    #pragma unroll
    for (int q = 0; q < 2; ++q) {
        short8v av = *(const short8v*)(ar + k0 + q * 8);
        #pragma unroll
        for (int j = 0; j < 8; ++j) {
            float a = bf2f((u16)av[j]);
            int k = k0 + q * 8 + j;
            s0 += a * Gb[k * 2 + 0];
            s1 += a * Gb[k * 2 + 1];
        }
    }
    #pragma unroll
    for (int off = 32; off; off >>= 1) {
        s0 += __shfl_down(s0, off);
        s1 += __shfl_down(s1, off);
    }
    if (lane == 0) { AG[row * 2 + 0] = s0; AG[row * 2 + 1] = s1; }
}

// ---------------------------------------------------------------------------
// energy
// ---------------------------------------------------------------------------
__global__ __launch_bounds__(256) void k_energy(const float* __restrict__ G,
                                                const float* __restrict__ AG,
                                                float* __restrict__ out) {
    __shared__ float red[256];
    int b = blockIdx.x, t = threadIdx.x;
    float s = 0.f;
    for (int n = t; n < NN; n += 256) {
        int bn = b * NN + n;
        float dx = G[bn * 2 + 0] - AG[bn * 2 + 0];
        float dy = G[bn * 2 + 1] - AG[bn * 2 + 1];
        s += sqrtf(dx * dx + dy * dy + 1e-10f);
    }
    red[t] = s;
    __syncthreads();
    for (int off = 128; off > 0; off >>= 1) {
        if (t < off) red[t] += red[t + off];
        __syncthreads();
    }
    if (t == 0) out[b] = red[0] / (float)NN;
}

// ---------------------------------------------------------------------------
extern "C" void kernel_launch(void* const* d_in, const int* in_sizes, int n_in,
                              void* d_out, int out_size, void* d_ws, size_t ws_size,
                              hipStream_t stream) {
    const float* features   = (const float*)d_in[0];
    const float* base_point = (const float*)d_in[1];
    const float* adj        = (const float*)d_in[2];
    const float* mask       = (const float*)d_in[3];
    const float* first_W    = (const float*)d_in[4];
    const float* first_b    = (const float*)d_in[5];
    const float* mid_W      = (const float*)d_in[6];
    const float* mid_b      = (const float*)d_in[7];
    const float* last_W     = (const float*)d_in[8];
    const float* last_b     = (const float*)d_in[9];
    const float* fc_W       = (const float*)d_in[10];
    const float* fc_b       = (const float*)d_in[11];
    float* out = (float*)d_out;
    char* p = (char*)d_ws;

    u16* adjh = (u16*)p;                 p += (size_t)BB * NN * NN * 2;
    u16* Xh   = (u16*)p;                 p += (size_t)BN * K1 * 2;
    u16* XhT  = (u16*)p;                 p += (size_t)BB * 256 * 1024 * 2;
    u16* Whf  = (u16*)p;                 p += (size_t)2 * 256 * K1 * 2;
    u16* Whm  = (u16*)p;                 p += (size_t)6 * 4 * 256 * 256 * 2;
    u16* Whl  = (u16*)p;                 p += (size_t)2 * 256 * 256 * 2;
    u16* AGG  = (u16*)p;                 p += (size_t)BN * 256 * 2;
    u16* Hn   = (u16*)p;                 p += (size_t)BN * 256 * 2;
    u16* HnT  = (u16*)p;                 p += (size_t)BB * 256 * 1024 * 2;
    u16* On   = (u16*)p;                 p += (size_t)BN * 256 * 2;
    u16* OnT  = (u16*)p;                 p += (size_t)BB * 256 * 1024 * 2;
    float* G  = (float*)p;               p += (size_t)BN * 2 * 4;
    float* AG = (float*)p;               p += (size_t)BN * 2 * 4;

    k_cast4<<<2048, 256, 0, stream>>>(adj, adjh, (long)BB * NN * NN / 4);
    k_cast4<<<256, 256, 0, stream>>>(mid_W, Whm, (long)6 * 4 * 256 * 256 / 4);
    k_cast4<<<64, 256, 0, stream>>>(last_W, Whl, (long)2 * 256 * 256 / 4);
    k_castW1<<<(2 * 256 * K1 + 255) / 256, 256, 0, stream>>>(first_W, Whf);
    k_interp<<<BN, 128, 0, stream>>>(features, base_point, Xh, XhT);

    const long sA = (long)NN * NN, sB = 256L * 1024, sC = (long)NN * 256;
    dim3 gAgg(2, 8, 16), gGc(2, 128, 1), blk(256);

    // first layer
    k_mm<<<gAgg, blk, 0, stream>>>(adjh, NN, nullptr, 0, XhT, nullptr, NN, 16,
                                   nullptr, nullptr, nullptr, 0,
                                   AGG, 256, nullptr, 1, sA, sB, sC);
    k_mm<<<gGc, blk, 0, stream>>>(Xh, K1, AGG, 256, Whf, Whf + 256 * K1, K1, 3,
                                  first_b, first_b + 256, nullptr, 1,
                                  Hn, 256, HnT, 0, 0, 0, 0);

    for (int i = 0; i < 6; ++i) {
        const u16* W = Whm + (size_t)i * 4 * 256 * 256;
        const float* bb = mid_b + (size_t)i * 4 * 256;
        k_mm<<<gAgg, blk, 0, stream>>>(adjh, NN, nullptr, 0, HnT, nullptr, NN, 16,
                                       nullptr, nullptr, nullptr, 0,
                                       AGG, 256, nullptr, 1, sA, sB, sC);
        k_mm<<<gGc, blk, 0, stream>>>(Hn, 256, AGG, 256, W, W + 65536, 256, 4,
                                      bb, bb + 256, nullptr, 1,
                                      On, 256, OnT, 0, 0, 0, 0);
        k_mm<<<gAgg, blk, 0, stream>>>(adjh, NN, nullptr, 0, OnT, nullptr, NN, 16,
                                       nullptr, nullptr, nullptr, 0,
                                       AGG, 256, nullptr, 1, sA, sB, sC);
        k_mm<<<gGc, blk, 0, stream>>>(On, 256, AGG, 256, W + 2 * 65536, W + 3 * 65536, 256, 4,
                                      bb + 512, bb + 768, Hn, 1,
                                      Hn, 256, HnT, 0, 0, 0, 0);
    }

    // last layer
    k_mm<<<gAgg, blk, 0, stream>>>(adjh, NN, nullptr, 0, HnT, nullptr, NN, 16,
                                   nullptr, nullptr, nullptr, 0,
                                   AGG, 256, nullptr, 1, sA, sB, sC);
    k_mm<<<gGc, blk, 0, stream>>>(Hn, 256, AGG, 256, Whl, Whl + 65536, 256, 4,
                                  last_b, last_b + 256, nullptr, 1,
                                  On, 256, nullptr, 0, 0, 0, 0);

    // head + energy
    k_fc<<<BN / 256, 256, 0, stream>>>(On, fc_W, fc_b, base_point, mask, out, G);
    k_adjg<<<BN / 4, 256, 0, stream>>>(adjh, G, AG);
    k_energy<<<BB, 256, 0, stream>>>(G, AG, out);
}

// Round 3
// 637.659 us; speedup vs baseline: 5.9981x; 1.3943x over previous
//
#include <hip/hip_runtime.h>
#include <cmath>

#define BB 16
#define CC 128
#define HH 128
#define WW 128
#define NN 1024
#define SS 256
#define BN (BB*NN)
#define K1 192            // first-layer K padded: 130 -> 192 (3 x 64)

typedef short short8v __attribute__((ext_vector_type(8)));
typedef float f32x4 __attribute__((ext_vector_type(4)));
typedef unsigned short u16;

__device__ __forceinline__ u16 f2bf(float f) {
    unsigned u = __builtin_bit_cast(unsigned, f);
    unsigned r = (u + 0x7FFFu + ((u >> 16) & 1u)) >> 16;
    return (u16)r;
}
__device__ __forceinline__ float bf2f(u16 h) {
    unsigned u = ((unsigned)h) << 16;
    return __builtin_bit_cast(float, u);
}

// ---------------------------------------------------------------------------
// casts
// ---------------------------------------------------------------------------
__global__ void k_cast4(const float* __restrict__ s, u16* __restrict__ d, long n4) {
    long i = (long)blockIdx.x * blockDim.x + threadIdx.x;
    long st = (long)gridDim.x * blockDim.x;
    for (; i < n4; i += st) {
        float4 v = ((const float4*)s)[i];
        ushort4 o;
        o.x = f2bf(v.x); o.y = f2bf(v.y); o.z = f2bf(v.z); o.w = f2bf(v.w);
        ((ushort4*)d)[i] = o;
    }
}

// first_W [2][256][130] -> bf16 [2][256][192] zero-padded
__global__ void k_castW1(const float* __restrict__ s, u16* __restrict__ d) {
    int idx = blockIdx.x * blockDim.x + threadIdx.x;
    if (idx >= 2 * 256 * K1) return;
    int k = idx % K1, r = idx / K1;
    d[idx] = (k < 130) ? f2bf(s[r * 130 + k]) : (u16)0;
}

// ---------------------------------------------------------------------------
// features [16][128][16384] f32 -> featT [16][16384][128] bf16 (tiled transpose)
// grid (16384/128, 16), block 256
// ---------------------------------------------------------------------------
__global__ __launch_bounds__(256) void k_ftrans(const float* __restrict__ f,
                                                u16* __restrict__ ft) {
    __shared__ u16 T[128][132];
    int b = blockIdx.y, hw0 = blockIdx.x * 128;
    int t = threadIdx.x;
    const float* fb = f + (long)b * CC * (HH * WW);
    #pragma unroll
    for (int p = 0; p < 16; ++p) {           // 8 c-rows per pass
        int c = p * 8 + (t >> 5);
        int x = (t & 31) * 4;
        float4 v = *(const float4*)(fb + (long)c * (HH * WW) + hw0 + x);
        T[x + 0][c] = f2bf(v.x); T[x + 1][c] = f2bf(v.y);
        T[x + 2][c] = f2bf(v.z); T[x + 3][c] = f2bf(v.w);
    }
    __syncthreads();
    #pragma unroll
    for (int p = 0; p < 8; ++p) {            // 16 hw-rows per pass
        int hw = p * 16 + (t >> 4);
        int c8 = (t & 15) * 8;
        short8v v = *(const short8v*)&T[hw][c8];
        *(short8v*)(ft + ((long)b * 16384 + hw0 + hw) * 128 + c8) = v;
    }
}

// ---------------------------------------------------------------------------
// interp: wave per node; lane = (corner<<4)|chunk. featT rows are 256B.
// writes Xh [BN][192] (cols 128/129 = px,py ; 130..191 = 0)
// ---------------------------------------------------------------------------
__global__ __launch_bounds__(256) void k_interp(const u16* __restrict__ featT,
                                                const float* __restrict__ base_point,
                                                u16* __restrict__ Xh) {
    int t = threadIdx.x;
    int lane = t & 63, w = t >> 6;
    int bn = blockIdx.x * 4 + w;
    int b = bn >> 10;
    float px = base_point[bn * 2 + 0];
    float py = base_point[bn * 2 + 1];
    float Xs = px * WW, Ys = py * HH;
    float X0f = floorf(Xs), Y0f = floorf(Ys);
    float fx = Xs - X0f, fy = Ys - Y0f;
    int x0 = min(max((int)X0f, 0), WW - 1);
    int x1 = min(max((int)(X0f + 1.f), 0), WW - 1);
    int y0 = min(max((int)Y0f, 0), HH - 1);
    int y1 = min(max((int)(Y0f + 1.f), 0), HH - 1);
    int corner = lane >> 4, chunk = lane & 15;
    int xi = (corner & 2) ? x1 : x0;
    int yi = (corner & 1) ? y1 : y0;
    float wgt = ((corner & 2) ? fx : 1.f - fx) * ((corner & 1) ? fy : 1.f - fy);
    const u16* fp = featT + ((long)b * 16384 + yi * WW + xi) * 128 + chunk * 8;
    short8v v = *(const short8v*)fp;
    float a[8];
    #pragma unroll
    for (int j = 0; j < 8; ++j) a[j] = wgt * bf2f((u16)v[j]);
    #pragma unroll
    for (int j = 0; j < 8; ++j) {
        a[j] += __shfl_xor(a[j], 16);
        a[j] += __shfl_xor(a[j], 32);
    }
    if (lane < 16) {
        short8v o;
        #pragma unroll
        for (int j = 0; j < 8; ++j) o[j] = (short)f2bf(a[j]);
        *(short8v*)(Xh + (long)bn * K1 + chunk * 8) = o;
    } else if (lane < 24) {
        short8v o = {};
        if (lane == 16) { o[0] = (short)f2bf(px); o[1] = (short)f2bf(py); }
        *(short8v*)(Xh + (long)bn * K1 + 128 + (lane - 16) * 8) = o;
    }
}

// ---------------------------------------------------------------------------
// Xh [16384][192] -> XhT [16][256][1024], rows 192..255 zeroed
// grid (1024/128, 16), block 256
// ---------------------------------------------------------------------------
__global__ __launch_bounds__(256) void k_xt(const u16* __restrict__ Xh,
                                            u16* __restrict__ XhT) {
    __shared__ u16 T[192][136];
    int b = blockIdx.y, n0 = blockIdx.x * 128;
    int t = threadIdx.x;
    #pragma unroll
    for (int p = 0; p < 12; ++p) {
        int idx = p * 256 + t;            // 3072 chunks = 128 nodes x 24
        int node = idx / 24, ch = idx % 24;
        short8v v = *(const short8v*)(Xh + ((long)(b * 1024 + n0 + node)) * K1 + ch * 8);
        #pragma unroll
        for (int j = 0; j < 8; ++j) T[ch * 8 + j][node] = (u16)v[j];
    }
    __syncthreads();
    #pragma unroll
    for (int p = 0; p < 12; ++p) {
        int c = p * 16 + (t >> 4);
        int m8 = (t & 15) * 8;
        short8v v = *(const short8v*)&T[c][m8];
        *(short8v*)(XhT + ((long)b * 256 + c) * 1024 + n0 + m8) = v;
    }
    #pragma unroll
    for (int p = 0; p < 4; ++p) {
        int c = 192 + p * 16 + (t >> 4);
        int m8 = (t & 15) * 8;
        short8v z = {};
        *(short8v*)(XhT + ((long)b * 256 + c) * 1024 + n0 + m8) = z;
    }
}

// ---------------------------------------------------------------------------
// MFMA GEMM, 8 waves, 128x128 tile, BK=64, double-buffered LDS w/ early stage
// C = [A0|A1] @ [B0|B1]^T (+bias +res, relu). B stored [n][K] k-contig.
// ---------------------------------------------------------------------------
__global__ __launch_bounds__(512) void k_mm(
    const u16* __restrict__ A0, int lda0, int nK0,
    const u16* __restrict__ A1, int lda1, int nK1,
    const u16* __restrict__ B0, int ldb0,
    const u16* __restrict__ B1, int ldb1,
    const float* __restrict__ bias0, const float* __restrict__ bias1,
    const u16* __restrict__ res, int do_relu,
    u16* __restrict__ outN, int ldoN,
    u16* __restrict__ outT,
    int batched, long sA, long sB, long sC) {

    __shared__ u16 lds[32768];               // 64 KB: 2 x (As 16KB + Bs 16KB)

    int t = threadIdx.x;
    int lane = t & 63, w = t >> 6;           // 8 waves
    int wr = w >> 1, wc = w & 1;             // 4x2 waves of 32x64
    int c0 = blockIdx.x * 128;
    long row0 = (long)blockIdx.y * 128;
    const u16* Ab0 = A0;
    const u16* Bb0 = B0;
    u16* oN = outN;
    if (batched) {
        int b = blockIdx.z;
        Ab0 += (long)b * sA;
        Bb0 += (long)b * sB;
        oN  += (long)b * sC;
    }

    int tot = nK0 + nK1;
    f32x4 acc[2][4] = {};

    auto stage = [&](int s, int bufbase) {
        const u16* Ap; int lda; const u16* Bp; int ldb; int kt;
        if (s < nK0) { Ap = Ab0; lda = lda0; Bp = Bb0; ldb = ldb0; kt = s * 64; }
        else         { Ap = A1;  lda = lda1; Bp = B1;  ldb = ldb1; kt = (s - nK0) * 64; }
        u16* As = lds + bufbase;
        u16* Bs = lds + bufbase + 8192;
        #pragma unroll
        for (int q = 0; q < 2; ++q) {
            int rb = w * 16 + q * 8;
            int row = rb + (lane >> 3);
            int koff = kt + (((lane & 7) ^ (row & 7)) << 3);
            __builtin_amdgcn_global_load_lds(
                (const __attribute__((address_space(1))) void*)(Ap + (row0 + row) * lda + koff),
                (__attribute__((address_space(3))) void*)(As + rb * 64), 16, 0, 0);
            __builtin_amdgcn_global_load_lds(
                (const __attribute__((address_space(1))) void*)(Bp + (long)(c0 + row) * ldb + koff),
                (__attribute__((address_space(3))) void*)(Bs + rb * 64), 16, 0, 0);
        }
    };

    stage(0, 0);
    __syncthreads();

    for (int s = 0; s < tot; ++s) {
        int cur = (s & 1) * 16384;
        if (s + 1 < tot) stage(s + 1, 16384 - cur);   // issue-early prefetch
        const u16* As = lds + cur;
        const u16* Bs = lds + cur + 8192;
        #pragma unroll
        for (int kk = 0; kk < 2; ++kk) {
            short8v a[2], bfr[4];
            #pragma unroll
            for (int m = 0; m < 2; ++m) {
                int row = wr * 32 + m * 16 + (lane & 15);
                int sl = (kk * 4 + (lane >> 4)) ^ (row & 7);
                a[m] = *(const short8v*)(As + row * 64 + sl * 8);
            }
            #pragma unroll
            for (int n = 0; n < 4; ++n) {
                int row = wc * 64 + n * 16 + (lane & 15);
                int sl = (kk * 4 + (lane >> 4)) ^ (row & 7);
                bfr[n] = *(const short8v*)(Bs + row * 64 + sl * 8);
            }
            #pragma unroll
            for (int m = 0; m < 2; ++m)
                #pragma unroll
                for (int n = 0; n < 4; ++n)
                    acc[m][n] = __builtin_amdgcn_mfma_f32_16x16x32_bf16(
                        a[m], bfr[n], acc[m][n], 0, 0, 0);
        }
        __syncthreads();
    }

    // ---- epilogue ----
    int mbase = wr * 32, nbase = wc * 64;
    u16 vals[2][4][4];
    #pragma unroll
    for (int m = 0; m < 2; ++m)
        #pragma unroll
        for (int n = 0; n < 4; ++n)
            #pragma unroll
            for (int r = 0; r < 4; ++r) {
                int rr = mbase + m * 16 + (lane >> 4) * 4 + r;
                int cc = nbase + n * 16 + (lane & 15);
                long grow = row0 + rr;
                int gcol = c0 + cc;
                float v = acc[m][n][r];
                if (bias0) v += bias0[gcol] + bias1[gcol];
                if (res)   v += bf2f(res[grow * ldoN + gcol]);
                if (do_relu) v = fmaxf(v, 0.f);
                u16 hv = f2bf(v);
                oN[grow * ldoN + gcol] = hv;
                vals[m][n][r] = hv;
            }

    if (outT) {
        u16 (*T)[136] = (u16(*)[136])lds;     // 128 x 136 = 34.8 KB
        __syncthreads();
        #pragma unroll
        for (int m = 0; m < 2; ++m)
            #pragma unroll
            for (int n = 0; n < 4; ++n)
                #pragma unroll
                for (int r = 0; r < 4; ++r) {
                    int rr = mbase + m * 16 + (lane >> 4) * 4 + r;
                    int cc = nbase + n * 16 + (lane & 15);
                    T[cc][rr] = vals[m][n][r];
                }
        __syncthreads();
        int bb2 = (int)(row0 >> 10);
        long nodeBase = row0 & 1023;
        #pragma unroll
        for (int p = 0; p < 4; ++p) {
            int c = p * 32 + (t >> 4);
            int moff = (t & 15) * 8;
            short8v vv = *(const short8v*)(&T[c][moff]);
            *(short8v*)(outT + ((long)bb2 * 256 + c0 + c) * 1024 + nodeBase + moff) = vv;
        }
    }
}

// ---------------------------------------------------------------------------
// FC head
// ---------------------------------------------------------------------------
__global__ void k_fc(const u16* __restrict__ Hf,
                     const float* __restrict__ fcW, const float* __restrict__ fcb,
                     const float* __restrict__ base_point,
                     const float* __restrict__ mask,
                     float* __restrict__ out, float* __restrict__ G) {
    int bn = blockIdx.x * blockDim.x + threadIdx.x;
    if (bn >= BN) return;
    const u16* hr = Hf + (long)bn * SS;
    float a0 = fcb[0], a1 = fcb[1];
    for (int k = 0; k < SS; k += 8) {
        short8v v = *(const short8v*)(hr + k);
        #pragma unroll
        for (int j = 0; j < 8; ++j) {
            float f = bf2f((u16)v[j]);
            a0 += f * fcW[k + j];
            a1 += f * fcW[SS + k + j];
        }
    }
    float m  = mask[bn];
    float p0 = base_point[bn * 2 + 0], p1 = base_point[bn * 2 + 1];
    float g0 = a0 * m, g1 = a1 * m;
    out[16 + bn * 2 + 0] = p0 + g0;
    out[16 + bn * 2 + 1] = p1 + g1;
    out[16 + BN * 2 + bn * 2 + 0] = a0;
    out[16 + BN * 2 + bn * 2 + 1] = a1;
    G[bn * 2 + 0] = g0;
    G[bn * 2 + 1] = g1;
}

// ---------------------------------------------------------------------------
// AG = adj @ G (fp32 G, bf16 adj); one wave per output row
// ---------------------------------------------------------------------------
__global__ __launch_bounds__(256) void k_adjg(const u16* __restrict__ adjh,
                                              const float* __restrict__ G,
                                              float* __restrict__ AG) {
    int w = threadIdx.x >> 6, lane = threadIdx.x & 63;
    long row = (long)blockIdx.x * 4 + w;
    int b = (int)(row >> 10);
    const u16* ar = adjh + ((long)b * NN + (row & 1023)) * NN;
    const float* Gb = G + (long)b * NN * 2;
    float s0 = 0.f, s1 = 0.f;
    int k0 = lane * 16;
    #pragma unroll
    for (int q = 0; q < 2; ++q) {
        short8v av = *(const short8v*)(ar + k0 + q * 8);
        #pragma unroll
        for (int j = 0; j < 8; ++j) {
            float a = bf2f((u16)av[j]);
            int k = k0 + q * 8 + j;
            s0 += a * Gb[k * 2 + 0];
            s1 += a * Gb[k * 2 + 1];
        }
    }
    #pragma unroll
    for (int off = 32; off; off >>= 1) {
        s0 += __shfl_down(s0, off);
        s1 += __shfl_down(s1, off);
    }
    if (lane == 0) { AG[row * 2 + 0] = s0; AG[row * 2 + 1] = s1; }
}

// ---------------------------------------------------------------------------
// energy
// ---------------------------------------------------------------------------
__global__ __launch_bounds__(256) void k_energy(const float* __restrict__ G,
                                                const float* __restrict__ AG,
                                                float* __restrict__ out) {
    __shared__ float red[256];
    int b = blockIdx.x, t = threadIdx.x;
    float s = 0.f;
    for (int n = t; n < NN; n += 256) {
        int bn = b * NN + n;
        float dx = G[bn * 2 + 0] - AG[bn * 2 + 0];
        float dy = G[bn * 2 + 1] - AG[bn * 2 + 1];
        s += sqrtf(dx * dx + dy * dy + 1e-10f);
    }
    red[t] = s;
    __syncthreads();
    for (int off = 128; off > 0; off >>= 1) {
        if (t < off) red[t] += red[t + off];
        __syncthreads();
    }
    if (t == 0) out[b] = red[0] / (float)NN;
}

// ---------------------------------------------------------------------------
extern "C" void kernel_launch(void* const* d_in, const int* in_sizes, int n_in,
                              void* d_out, int out_size, void* d_ws, size_t ws_size,
                              hipStream_t stream) {
    const float* features   = (const float*)d_in[0];
    const float* base_point = (const float*)d_in[1];
    const float* adj        = (const float*)d_in[2];
    const float* mask       = (const float*)d_in[3];
    const float* first_W    = (const float*)d_in[4];
    const float* first_b    = (const float*)d_in[5];
    const float* mid_W      = (const float*)d_in[6];
    const float* mid_b      = (const float*)d_in[7];
    const float* last_W     = (const float*)d_in[8];
    const float* last_b     = (const float*)d_in[9];
    const float* fc_W       = (const float*)d_in[10];
    const float* fc_b       = (const float*)d_in[11];
    float* out = (float*)d_out;
    char* p = (char*)d_ws;

    // Region 0 (67.1 MB): featT lives here first; after interp it is dead and
    // the region is reused for adjh / AGG / Hn / On / G / AG.
    u16*  featT = (u16*)p;
    u16*  adjh  = (u16*)p;                                   // 33.55 MB
    u16*  AGG   = (u16*)(p + 33554432);                      //  8.39 MB
    u16*  Hn    = (u16*)(p + 33554432 + 8388608);            //  8.39 MB
    u16*  On    = (u16*)(p + 33554432 + 2 * 8388608);        //  8.39 MB
    float* G    = (float*)(p + 33554432 + 3 * 8388608);      //  0.13 MB
    float* AG   = G + (size_t)BN * 2;                        //  0.13 MB
    p += (size_t)BB * 16384 * 128 * 2;                       // 67108864

    u16* Xh  = (u16*)p;  p += (size_t)BN * K1 * 2;
    u16* XhT = (u16*)p;  p += (size_t)BB * 256 * 1024 * 2;
    u16* HnT = (u16*)p;  p += (size_t)BB * 256 * 1024 * 2;
    u16* OnT = (u16*)p;  p += (size_t)BB * 256 * 1024 * 2;
    u16* Whf = (u16*)p;  p += (size_t)2 * 256 * K1 * 2;
    u16* Whm = (u16*)p;  p += (size_t)6 * 4 * 256 * 256 * 2;
    u16* Whl = (u16*)p;  p += (size_t)2 * 256 * 256 * 2;

    // interp path first (featT region), then overwrite region with adjh etc.
    k_ftrans<<<dim3(128, 16), 256, 0, stream>>>(features, featT);
    k_interp<<<BN / 4, 256, 0, stream>>>(featT, base_point, Xh);
    k_xt<<<dim3(8, 16), 256, 0, stream>>>(Xh, XhT);

    k_cast4<<<2048, 256, 0, stream>>>(adj, adjh, (long)BB * NN * NN / 4);
    k_cast4<<<256, 256, 0, stream>>>(mid_W, Whm, (long)6 * 4 * 256 * 256 / 4);
    k_cast4<<<64, 256, 0, stream>>>(last_W, Whl, (long)2 * 256 * 256 / 4);
    k_castW1<<<(2 * 256 * K1 + 255) / 256, 256, 0, stream>>>(first_W, Whf);

    const long sA = (long)NN * NN, sB = 256L * 1024, sC = (long)NN * 256;
    dim3 gAgg(2, 8, 16), gGc(2, 128, 1), blk(512);

    // first layer
    k_mm<<<gAgg, blk, 0, stream>>>(adjh, NN, 16, nullptr, 0, 0, XhT, NN, nullptr, 0,
                                   nullptr, nullptr, nullptr, 0,
                                   AGG, 256, nullptr, 1, sA, sB, sC);
    k_mm<<<gGc, blk, 0, stream>>>(Xh, K1, 3, AGG, 256, 3, Whf, K1, Whf + 256 * K1, K1,
                                  first_b, first_b + 256, nullptr, 1,
                                  Hn, 256, HnT, 0, 0, 0, 0);

    for (int i = 0; i < 6; ++i) {
        const u16* W = Whm + (size_t)i * 4 * 256 * 256;
        const float* bb = mid_b + (size_t)i * 4 * 256;
        k_mm<<<gAgg, blk, 0, stream>>>(adjh, NN, 16, nullptr, 0, 0, HnT, NN, nullptr, 0,
                                       nullptr, nullptr, nullptr, 0,
                                       AGG, 256, nullptr, 1, sA, sB, sC);
        k_mm<<<gGc, blk, 0, stream>>>(Hn, 256, 4, AGG, 256, 4, W, 256, W + 65536, 256,
                                      bb, bb + 256, nullptr, 1,
                                      On, 256, OnT, 0, 0, 0, 0);
        k_mm<<<gAgg, blk, 0, stream>>>(adjh, NN, 16, nullptr, 0, 0, OnT, NN, nullptr, 0,
                                       nullptr, nullptr, nullptr, 0,
                                       AGG, 256, nullptr, 1, sA, sB, sC);
        k_mm<<<gGc, blk, 0, stream>>>(On, 256, 4, AGG, 256, 4,
                                      W + 2 * 65536, 256, W + 3 * 65536, 256,
                                      bb + 512, bb + 768, Hn, 1,
                                      Hn, 256, HnT, 0, 0, 0, 0);
    }

    // last layer
    k_mm<<<gAgg, blk, 0, stream>>>(adjh, NN, 16, nullptr, 0, 0, HnT, NN, nullptr, 0,
                                   nullptr, nullptr, nullptr, 0,
                                   AGG, 256, nullptr, 1, sA, sB, sC);
    k_mm<<<gGc, blk, 0, stream>>>(Hn, 256, 4, AGG, 256, 4, Whl, 256, Whl + 65536, 256,
                                  last_b, last_b + 256, nullptr, 1,
                                  On, 256, nullptr, 0, 0, 0, 0);

    // head + energy
    k_fc<<<BN / 256, 256, 0, stream>>>(On, fc_W, fc_b, base_point, mask, out, G);
    k_adjg<<<BN / 4, 256, 0, stream>>>(adjh, G, AG);
    k_energy<<<BB, 256, 0, stream>>>(G, AG, out);
}

// Round 4
// 606.762 us; speedup vs baseline: 6.3036x; 1.0509x over previous
//
#include <hip/hip_runtime.h>
#include <cmath>

#define BB 16
#define CC 128
#define HH 128
#define WW 128
#define NN 1024
#define SS 256
#define BN (BB*NN)
#define K1 192            // first-layer K padded: 130 -> 192 (3 x 64)

typedef short short8v __attribute__((ext_vector_type(8)));
typedef float f32x4 __attribute__((ext_vector_type(4)));
typedef unsigned short u16;

__device__ __forceinline__ u16 f2bf(float f) {
    unsigned u = __builtin_bit_cast(unsigned, f);
    unsigned r = (u + 0x7FFFu + ((u >> 16) & 1u)) >> 16;
    return (u16)r;
}
__device__ __forceinline__ float bf2f(u16 h) {
    unsigned u = ((unsigned)h) << 16;
    return __builtin_bit_cast(float, u);
}

// ---------------------------------------------------------------------------
// casts
// ---------------------------------------------------------------------------
__global__ void k_cast4(const float* __restrict__ s, u16* __restrict__ d, long n4) {
    long i = (long)blockIdx.x * blockDim.x + threadIdx.x;
    long st = (long)gridDim.x * blockDim.x;
    for (; i < n4; i += st) {
        float4 v = ((const float4*)s)[i];
        ushort4 o;
        o.x = f2bf(v.x); o.y = f2bf(v.y); o.z = f2bf(v.z); o.w = f2bf(v.w);
        ((ushort4*)d)[i] = o;
    }
}

// first_W [2][256][130] -> bf16 [2][256][192] zero-padded
__global__ void k_castW1(const float* __restrict__ s, u16* __restrict__ d) {
    int idx = blockIdx.x * blockDim.x + threadIdx.x;
    if (idx >= 2 * 256 * K1) return;
    int k = idx % K1, r = idx / K1;
    d[idx] = (k < 130) ? f2bf(s[r * 130 + k]) : (u16)0;
}

// ---------------------------------------------------------------------------
// features [16][128][16384] f32 -> featT [16][16384][128] bf16 (tiled transpose)
// grid (16384/128, 16), block 256
// ---------------------------------------------------------------------------
__global__ __launch_bounds__(256) void k_ftrans(const float* __restrict__ f,
                                                u16* __restrict__ ft) {
    __shared__ u16 T[128][132];
    int b = blockIdx.y, hw0 = blockIdx.x * 128;
    int t = threadIdx.x;
    const float* fb = f + (long)b * CC * (HH * WW);
    #pragma unroll
    for (int p = 0; p < 16; ++p) {           // 8 c-rows per pass
        int c = p * 8 + (t >> 5);
        int x = (t & 31) * 4;
        float4 v = *(const float4*)(fb + (long)c * (HH * WW) + hw0 + x);
        T[x + 0][c] = f2bf(v.x); T[x + 1][c] = f2bf(v.y);
        T[x + 2][c] = f2bf(v.z); T[x + 3][c] = f2bf(v.w);
    }
    __syncthreads();
    #pragma unroll
    for (int p = 0; p < 8; ++p) {            // 16 hw-rows per pass
        int hw = p * 16 + (t >> 4);
        int c8 = (t & 15) * 8;
        short8v v = *(const short8v*)&T[hw][c8];
        *(short8v*)(ft + ((long)b * 16384 + hw0 + hw) * 128 + c8) = v;
    }
}

// ---------------------------------------------------------------------------
// interp: wave per node; lane = (corner<<4)|chunk. featT rows are 256B.
// writes Xh [BN][192] (cols 128/129 = px,py ; 130..191 = 0)
// ---------------------------------------------------------------------------
__global__ __launch_bounds__(256) void k_interp(const u16* __restrict__ featT,
                                                const float* __restrict__ base_point,
                                                u16* __restrict__ Xh) {
    int t = threadIdx.x;
    int lane = t & 63, w = t >> 6;
    int bn = blockIdx.x * 4 + w;
    int b = bn >> 10;
    float px = base_point[bn * 2 + 0];
    float py = base_point[bn * 2 + 1];
    float Xs = px * WW, Ys = py * HH;
    float X0f = floorf(Xs), Y0f = floorf(Ys);
    float fx = Xs - X0f, fy = Ys - Y0f;
    int x0 = min(max((int)X0f, 0), WW - 1);
    int x1 = min(max((int)(X0f + 1.f), 0), WW - 1);
    int y0 = min(max((int)Y0f, 0), HH - 1);
    int y1 = min(max((int)(Y0f + 1.f), 0), HH - 1);
    int corner = lane >> 4, chunk = lane & 15;
    int xi = (corner & 2) ? x1 : x0;
    int yi = (corner & 1) ? y1 : y0;
    float wgt = ((corner & 2) ? fx : 1.f - fx) * ((corner & 1) ? fy : 1.f - fy);
    const u16* fp = featT + ((long)b * 16384 + yi * WW + xi) * 128 + chunk * 8;
    short8v v = *(const short8v*)fp;
    float a[8];
    #pragma unroll
    for (int j = 0; j < 8; ++j) a[j] = wgt * bf2f((u16)v[j]);
    #pragma unroll
    for (int j = 0; j < 8; ++j) {
        a[j] += __shfl_xor(a[j], 16);
        a[j] += __shfl_xor(a[j], 32);
    }
    if (lane < 16) {
        short8v o;
        #pragma unroll
        for (int j = 0; j < 8; ++j) o[j] = (short)f2bf(a[j]);
        *(short8v*)(Xh + (long)bn * K1 + chunk * 8) = o;
    } else if (lane < 24) {
        short8v o = {};
        if (lane == 16) { o[0] = (short)f2bf(px); o[1] = (short)f2bf(py); }
        *(short8v*)(Xh + (long)bn * K1 + 128 + (lane - 16) * 8) = o;
    }
}

// ---------------------------------------------------------------------------
// Xh [16384][192] -> XhT [16][256][1024], rows 192..255 zeroed
// grid (1024/128, 16), block 256
// ---------------------------------------------------------------------------
__global__ __launch_bounds__(256) void k_xt(const u16* __restrict__ Xh,
                                            u16* __restrict__ XhT) {
    __shared__ u16 T[192][136];
    int b = blockIdx.y, n0 = blockIdx.x * 128;
    int t = threadIdx.x;
    #pragma unroll
    for (int p = 0; p < 12; ++p) {
        int idx = p * 256 + t;            // 3072 chunks = 128 nodes x 24
        int node = idx / 24, ch = idx % 24;
        short8v v = *(const short8v*)(Xh + ((long)(b * 1024 + n0 + node)) * K1 + ch * 8);
        #pragma unroll
        for (int j = 0; j < 8; ++j) T[ch * 8 + j][node] = (u16)v[j];
    }
    __syncthreads();
    #pragma unroll
    for (int p = 0; p < 12; ++p) {
        int c = p * 16 + (t >> 4);
        int m8 = (t & 15) * 8;
        short8v v = *(const short8v*)&T[c][m8];
        *(short8v*)(XhT + ((long)b * 256 + c) * 1024 + n0 + m8) = v;
    }
    #pragma unroll
    for (int p = 0; p < 4; ++p) {
        int c = 192 + p * 16 + (t >> 4);
        int m8 = (t & 15) * 8;
        short8v z = {};
        *(short8v*)(XhT + ((long)b * 256 + c) * 1024 + n0 + m8) = z;
    }
}

// ---------------------------------------------------------------------------
// MFMA GEMM, 8 waves, 128x128 tile, BK=64.
// 3-stage LDS pipeline (96 KB), 2-deep prefetch, counted vmcnt, 1 barrier/step.
// C = [A0|A1] @ [B0|B1]^T (+bias +res, relu). B stored [n][K] k-contig.
// ---------------------------------------------------------------------------
__global__ __launch_bounds__(512) void k_mm(
    const u16* __restrict__ A0, int lda0, int nK0,
    const u16* __restrict__ A1, int lda1, int nK1,
    const u16* __restrict__ B0, int ldb0,
    const u16* __restrict__ B1, int ldb1,
    const float* __restrict__ bias0, const float* __restrict__ bias1,
    const u16* __restrict__ res, int do_relu,
    u16* __restrict__ outN, int ldoN,
    u16* __restrict__ outT,
    int batched, long sA, long sB, long sC) {

    __shared__ u16 lds[49152];               // 96 KB: 3 x (As 16KB + Bs 16KB)

    int t = threadIdx.x;
    int lane = t & 63, w = t >> 6;           // 8 waves
    int wr = w >> 1, wc = w & 1;             // 4x2 waves of 32x64
    int c0 = blockIdx.x * 128;
    long row0 = (long)blockIdx.y * 128;
    const u16* Ab0 = A0;
    const u16* Bb0 = B0;
    u16* oN = outN;
    if (batched) {
        int b = blockIdx.z;
        Ab0 += (long)b * sA;
        Bb0 += (long)b * sB;
        oN  += (long)b * sC;
    }

    int tot = nK0 + nK1;
    f32x4 acc[2][4] = {};

    auto stage = [&](int s, int bufbase) {   // issues 4 global_load_lds
        const u16* Ap; int lda; const u16* Bp; int ldb; int kt;
        if (s < nK0) { Ap = Ab0; lda = lda0; Bp = Bb0; ldb = ldb0; kt = s * 64; }
        else         { Ap = A1;  lda = lda1; Bp = B1;  ldb = ldb1; kt = (s - nK0) * 64; }
        u16* As = lds + bufbase;
        u16* Bs = lds + bufbase + 8192;
        #pragma unroll
        for (int q = 0; q < 2; ++q) {
            int rb = w * 16 + q * 8;
            int row = rb + (lane >> 3);
            int koff = kt + (((lane & 7) ^ (row & 7)) << 3);
            __builtin_amdgcn_global_load_lds(
                (const __attribute__((address_space(1))) void*)(Ap + (row0 + row) * lda + koff),
                (__attribute__((address_space(3))) void*)(As + rb * 64), 16, 0, 0);
            __builtin_amdgcn_global_load_lds(
                (const __attribute__((address_space(1))) void*)(Bp + (long)(c0 + row) * ldb + koff),
                (__attribute__((address_space(3))) void*)(Bs + rb * 64), 16, 0, 0);
        }
    };

    stage(0, 0);
    if (tot > 1) stage(1, 16384);

    int curb = 0, stb = 32768;
    for (int s = 0; s < tot; ++s) {
        // wait until this step's buffer has landed (keep newer prefetch flying)
        if (s + 1 < tot) { asm volatile("s_waitcnt vmcnt(4)" ::: "memory"); }
        else             { asm volatile("s_waitcnt vmcnt(0)" ::: "memory"); }
        __builtin_amdgcn_sched_barrier(0);
        __builtin_amdgcn_s_barrier();        // all waves: buffer landed, prev reads done
        if (s + 2 < tot) stage(s + 2, stb);  // overwrites buffer read 1 iter ago (safe)
        const u16* As = lds + curb;
        const u16* Bs = lds + curb + 8192;
        #pragma unroll
        for (int kk = 0; kk < 2; ++kk) {
            short8v a[2], bfr[4];
            #pragma unroll
            for (int m = 0; m < 2; ++m) {
                int row = wr * 32 + m * 16 + (lane & 15);
                int sl = (kk * 4 + (lane >> 4)) ^ (row & 7);
                a[m] = *(const short8v*)(As + row * 64 + sl * 8);
            }
            #pragma unroll
            for (int n = 0; n < 4; ++n) {
                int row = wc * 64 + n * 16 + (lane & 15);
                int sl = (kk * 4 + (lane >> 4)) ^ (row & 7);
                bfr[n] = *(const short8v*)(Bs + row * 64 + sl * 8);
            }
            #pragma unroll
            for (int m = 0; m < 2; ++m)
                #pragma unroll
                for (int n = 0; n < 4; ++n)
                    acc[m][n] = __builtin_amdgcn_mfma_f32_16x16x32_bf16(
                        a[m], bfr[n], acc[m][n], 0, 0, 0);
        }
        curb += 16384; if (curb == 49152) curb = 0;
        stb  += 16384; if (stb  == 49152) stb  = 0;
    }

    // ---- epilogue ----
    int mbase = wr * 32, nbase = wc * 64;
    u16 vals[2][4][4];
    #pragma unroll
    for (int m = 0; m < 2; ++m)
        #pragma unroll
        for (int n = 0; n < 4; ++n)
            #pragma unroll
            for (int r = 0; r < 4; ++r) {
                int rr = mbase + m * 16 + (lane >> 4) * 4 + r;
                int cc = nbase + n * 16 + (lane & 15);
                long grow = row0 + rr;
                int gcol = c0 + cc;
                float v = acc[m][n][r];
                if (bias0) v += bias0[gcol] + bias1[gcol];
                if (res)   v += bf2f(res[grow * ldoN + gcol]);
                if (do_relu) v = fmaxf(v, 0.f);
                u16 hv = f2bf(v);
                oN[grow * ldoN + gcol] = hv;
                vals[m][n][r] = hv;
            }

    if (outT) {
        u16 (*T)[136] = (u16(*)[136])lds;     // 128 x 136 = 34.8 KB
        __syncthreads();
        #pragma unroll
        for (int m = 0; m < 2; ++m)
            #pragma unroll
            for (int n = 0; n < 4; ++n)
                #pragma unroll
                for (int r = 0; r < 4; ++r) {
                    int rr = mbase + m * 16 + (lane >> 4) * 4 + r;
                    int cc = nbase + n * 16 + (lane & 15);
                    T[cc][rr] = vals[m][n][r];
                }
        __syncthreads();
        int bb2 = (int)(row0 >> 10);
        long nodeBase = row0 & 1023;
        #pragma unroll
        for (int p = 0; p < 4; ++p) {
            int c = p * 32 + (t >> 4);
            int moff = (t & 15) * 8;
            short8v vv = *(const short8v*)(&T[c][moff]);
            *(short8v*)(outT + ((long)bb2 * 256 + c0 + c) * 1024 + nodeBase + moff) = vv;
        }
    }
}

// ---------------------------------------------------------------------------
// FC head
// ---------------------------------------------------------------------------
__global__ void k_fc(const u16* __restrict__ Hf,
                     const float* __restrict__ fcW, const float* __restrict__ fcb,
                     const float* __restrict__ base_point,
                     const float* __restrict__ mask,
                     float* __restrict__ out, float* __restrict__ G) {
    int bn = blockIdx.x * blockDim.x + threadIdx.x;
    if (bn >= BN) return;
    const u16* hr = Hf + (long)bn * SS;
    float a0 = fcb[0], a1 = fcb[1];
    for (int k = 0; k < SS; k += 8) {
        short8v v = *(const short8v*)(hr + k);
        #pragma unroll
        for (int j = 0; j < 8; ++j) {
            float f = bf2f((u16)v[j]);
            a0 += f * fcW[k + j];
            a1 += f * fcW[SS + k + j];
        }
    }
    float m  = mask[bn];
    float p0 = base_point[bn * 2 + 0], p1 = base_point[bn * 2 + 1];
    float g0 = a0 * m, g1 = a1 * m;
    out[16 + bn * 2 + 0] = p0 + g0;
    out[16 + bn * 2 + 1] = p1 + g1;
    out[16 + BN * 2 + bn * 2 + 0] = a0;
    out[16 + BN * 2 + bn * 2 + 1] = a1;
    G[bn * 2 + 0] = g0;
    G[bn * 2 + 1] = g1;
}

// ---------------------------------------------------------------------------
// AG = adj @ G (fp32 G, bf16 adj); one wave per output row
// ---------------------------------------------------------------------------
__global__ __launch_bounds__(256) void k_adjg(const u16* __restrict__ adjh,
                                              const float* __restrict__ G,
                                              float* __restrict__ AG) {
    int w = threadIdx.x >> 6, lane = threadIdx.x & 63;
    long row = (long)blockIdx.x * 4 + w;
    int b = (int)(row >> 10);
    const u16* ar = adjh + ((long)b * NN + (row & 1023)) * NN;
    const float* Gb = G + (long)b * NN * 2;
    float s0 = 0.f, s1 = 0.f;
    int k0 = lane * 16;
    #pragma unroll
    for (int q = 0; q < 2; ++q) {
        short8v av = *(const short8v*)(ar + k0 + q * 8);
        #pragma unroll
        for (int j = 0; j < 8; ++j) {
            float a = bf2f((u16)av[j]);
            int k = k0 + q * 8 + j;
            s0 += a * Gb[k * 2 + 0];
            s1 += a * Gb[k * 2 + 1];
        }
    }
    #pragma unroll
    for (int off = 32; off; off >>= 1) {
        s0 += __shfl_down(s0, off);
        s1 += __shfl_down(s1, off);
    }
    if (lane == 0) { AG[row * 2 + 0] = s0; AG[row * 2 + 1] = s1; }
}

// ---------------------------------------------------------------------------
// energy
// ---------------------------------------------------------------------------
__global__ __launch_bounds__(256) void k_energy(const float* __restrict__ G,
                                                const float* __restrict__ AG,
                                                float* __restrict__ out) {
    __shared__ float red[256];
    int b = blockIdx.x, t = threadIdx.x;
    float s = 0.f;
    for (int n = t; n < NN; n += 256) {
        int bn = b * NN + n;
        float dx = G[bn * 2 + 0] - AG[bn * 2 + 0];
        float dy = G[bn * 2 + 1] - AG[bn * 2 + 1];
        s += sqrtf(dx * dx + dy * dy + 1e-10f);
    }
    red[t] = s;
    __syncthreads();
    for (int off = 128; off > 0; off >>= 1) {
        if (t < off) red[t] += red[t + off];
        __syncthreads();
    }
    if (t == 0) out[b] = red[0] / (float)NN;
}

// ---------------------------------------------------------------------------
extern "C" void kernel_launch(void* const* d_in, const int* in_sizes, int n_in,
                              void* d_out, int out_size, void* d_ws, size_t ws_size,
                              hipStream_t stream) {
    const float* features   = (const float*)d_in[0];
    const float* base_point = (const float*)d_in[1];
    const float* adj        = (const float*)d_in[2];
    const float* mask       = (const float*)d_in[3];
    const float* first_W    = (const float*)d_in[4];
    const float* first_b    = (const float*)d_in[5];
    const float* mid_W      = (const float*)d_in[6];
    const float* mid_b      = (const float*)d_in[7];
    const float* last_W     = (const float*)d_in[8];
    const float* last_b     = (const float*)d_in[9];
    const float* fc_W       = (const float*)d_in[10];
    const float* fc_b       = (const float*)d_in[11];
    float* out = (float*)d_out;
    char* p = (char*)d_ws;

    // Region 0 (67.1 MB): featT lives here first; after interp it is dead and
    // the region is reused for adjh / AGG / Hn / On / G / AG.
    u16*  featT = (u16*)p;
    u16*  adjh  = (u16*)p;                                   // 33.55 MB
    u16*  AGG   = (u16*)(p + 33554432);                      //  8.39 MB
    u16*  Hn    = (u16*)(p + 33554432 + 8388608);            //  8.39 MB
    u16*  On    = (u16*)(p + 33554432 + 2 * 8388608);        //  8.39 MB
    float* G    = (float*)(p + 33554432 + 3 * 8388608);      //  0.13 MB
    float* AG   = G + (size_t)BN * 2;                        //  0.13 MB
    p += (size_t)BB * 16384 * 128 * 2;                       // 67108864

    u16* Xh  = (u16*)p;  p += (size_t)BN * K1 * 2;
    u16* XhT = (u16*)p;  p += (size_t)BB * 256 * 1024 * 2;
    u16* HnT = (u16*)p;  p += (size_t)BB * 256 * 1024 * 2;
    u16* OnT = (u16*)p;  p += (size_t)BB * 256 * 1024 * 2;
    u16* Whf = (u16*)p;  p += (size_t)2 * 256 * K1 * 2;
    u16* Whm = (u16*)p;  p += (size_t)6 * 4 * 256 * 256 * 2;
    u16* Whl = (u16*)p;  p += (size_t)2 * 256 * 256 * 2;

    // interp path first (featT region), then overwrite region with adjh etc.
    k_ftrans<<<dim3(128, 16), 256, 0, stream>>>(features, featT);
    k_interp<<<BN / 4, 256, 0, stream>>>(featT, base_point, Xh);
    k_xt<<<dim3(8, 16), 256, 0, stream>>>(Xh, XhT);

    k_cast4<<<2048, 256, 0, stream>>>(adj, adjh, (long)BB * NN * NN / 4);
    k_cast4<<<256, 256, 0, stream>>>(mid_W, Whm, (long)6 * 4 * 256 * 256 / 4);
    k_cast4<<<64, 256, 0, stream>>>(last_W, Whl, (long)2 * 256 * 256 / 4);
    k_castW1<<<(2 * 256 * K1 + 255) / 256, 256, 0, stream>>>(first_W, Whf);

    const long sA = (long)NN * NN, sB = 256L * 1024, sC = (long)NN * 256;
    dim3 gAgg(2, 8, 16), gGc(2, 128, 1), blk(512);

    // first layer
    k_mm<<<gAgg, blk, 0, stream>>>(adjh, NN, 16, nullptr, 0, 0, XhT, NN, nullptr, 0,
                                   nullptr, nullptr, nullptr, 0,
                                   AGG, 256, nullptr, 1, sA, sB, sC);
    k_mm<<<gGc, blk, 0, stream>>>(Xh, K1, 3, AGG, 256, 3, Whf, K1, Whf + 256 * K1, K1,
                                  first_b, first_b + 256, nullptr, 1,
                                  Hn, 256, HnT, 0, 0, 0, 0);

    for (int i = 0; i < 6; ++i) {
        const u16* W = Whm + (size_t)i * 4 * 256 * 256;
        const float* bb = mid_b + (size_t)i * 4 * 256;
        k_mm<<<gAgg, blk, 0, stream>>>(adjh, NN, 16, nullptr, 0, 0, HnT, NN, nullptr, 0,
                                       nullptr, nullptr, nullptr, 0,
                                       AGG, 256, nullptr, 1, sA, sB, sC);
        k_mm<<<gGc, blk, 0, stream>>>(Hn, 256, 4, AGG, 256, 4, W, 256, W + 65536, 256,
                                      bb, bb + 256, nullptr, 1,
                                      On, 256, OnT, 0, 0, 0, 0);
        k_mm<<<gAgg, blk, 0, stream>>>(adjh, NN, 16, nullptr, 0, 0, OnT, NN, nullptr, 0,
                                       nullptr, nullptr, nullptr, 0,
                                       AGG, 256, nullptr, 1, sA, sB, sC);
        k_mm<<<gGc, blk, 0, stream>>>(On, 256, 4, AGG, 256, 4,
                                      W + 2 * 65536, 256, W + 3 * 65536, 256,
                                      bb + 512, bb + 768, Hn, 1,
                                      Hn, 256, HnT, 0, 0, 0, 0);
    }

    // last layer
    k_mm<<<gAgg, blk, 0, stream>>>(adjh, NN, 16, nullptr, 0, 0, HnT, NN, nullptr, 0,
                                   nullptr, nullptr, nullptr, 0,
                                   AGG, 256, nullptr, 1, sA, sB, sC);
    k_mm<<<gGc, blk, 0, stream>>>(Hn, 256, 4, AGG, 256, 4, Whl, 256, Whl + 65536, 256,
                                  last_b, last_b + 256, nullptr, 1,
                                  On, 256, nullptr, 0, 0, 0, 0);

    // head + energy
    k_fc<<<BN / 256, 256, 0, stream>>>(On, fc_W, fc_b, base_point, mask, out, G);
    k_adjg<<<BN / 4, 256, 0, stream>>>(adjh, G, AG);
    k_energy<<<BB, 256, 0, stream>>>(G, AG, out);
}